// Round 14
// baseline (551.326 us; speedup 1.0000x reference)
//
#include <hip/hip_runtime.h>
#include <cstdint>
#include <cstddef>

#define NB 16384
#define NA 8
#define NE 512
#define NK 1024   // 2E
#define NN 4096   // A*E

typedef __bf16 bf16x8 __attribute__((ext_vector_type(8)));
typedef float  f32x4  __attribute__((ext_vector_type(4)));
typedef uint16_t u16x8 __attribute__((ext_vector_type(8)));

__device__ __forceinline__ uint16_t cvt_bf16(float f) {
    uint32_t u = __builtin_bit_cast(uint32_t, f);
    u += 0x7fffu + ((u >> 16) & 1u);
    return (uint16_t)(u >> 16);
}

// legacy BK=32 chunk swizzle (k_prep only)
__device__ __forceinline__ int swz(int row) { return (row ^ (row >> 2)) & 3; }

// conflict-free BK=32 tile position (16B units): row-pair interleave + 3-bit XOR
// proven 0-conflict in R5..R13 PMC
__device__ __forceinline__ int cf_pos(int row, int c) {
    return ((row >> 1) << 3) + ((((row & 1) << 2) + c) ^ ((row >> 1) & 7));
}

__device__ __forceinline__ void gl_lds16(const void* g, void* l) {
    __builtin_amdgcn_global_load_lds(
        (__attribute__((address_space(1))) void*)(void*)g,
        (__attribute__((address_space(3))) void*)l, 16, 0, 0);
}

// ---- fused prep: lw/fwd/bwd transpose-cvt + img cvt + bvec, one launch ----
__device__ __forceinline__ void tcvt_tile(const float* __restrict__ src,
                                          uint16_t* __restrict__ dst,
                                          int R, int C, int c0, int r0, int t) {
    __shared__ float tile[32][33];
    int tx = t & 31, ty = t >> 5;
#pragma unroll
    for (int yy = 0; yy < 4; ++yy) {
        int r = ty + yy * 8;
        tile[r][tx] = src[(size_t)(r0 + r) * C + c0 + tx];
    }
    __syncthreads();
#pragma unroll
    for (int yy = 0; yy < 4; ++yy) {
        int c = ty + yy * 8;
        dst[(size_t)(c0 + c) * R + r0 + tx] = cvt_bf16(tile[tx][c]);
    }
}

__global__ __launch_bounds__(256) void k_pre(const float* __restrict__ lw,
                                             const float* __restrict__ fwd,
                                             const float* __restrict__ bwd,
                                             const float* __restrict__ img,
                                             const float* __restrict__ lb,
                                             uint16_t* __restrict__ lwT,
                                             uint16_t* __restrict__ fwdT,
                                             uint16_t* __restrict__ bwdT,
                                             uint16_t* __restrict__ imgb,
                                             float* __restrict__ bvec) {
    int b = blockIdx.x, t = threadIdx.x;
    if (b < 512) {
        int bx = b & 31, by = b >> 5;
        tcvt_tile(lw, lwT, NE, NK, bx * 32, by * 32, t);
    } else if (b < 2560) {
        int i = b - 512;
        int mat = i >> 8, bx = i & 15, by = (i >> 4) & 15;
        tcvt_tile(fwd + (size_t)mat * NE * NE, fwdT + (size_t)mat * NE * NE,
                  NE, NE, bx * 32, by * 32, t);
    } else if (b < 4608) {
        int i = b - 2560;
        int mat = i >> 8, bx = i & 15, by = (i >> 4) & 15;
        tcvt_tile(bwd + (size_t)mat * NE * NE, bwdT + (size_t)mat * NE * NE,
                  NE, NE, bx * 32, by * 32, t);
    } else if (b < 12800) {
        int i = (b - 4608) * 256 + t;
        float4 v = ((const float4*)img)[i];
        ushort4 o;
        o.x = cvt_bf16(v.x); o.y = cvt_bf16(v.y); o.z = cvt_bf16(v.z); o.w = cvt_bf16(v.w);
        ((ushort4*)imgb)[i] = o;
    } else {
        int i = b - 12800;
        int a = i >> 4, i0 = (i & 15) * 32;
        float s0 = 0.f, s1 = 0.f;
#pragma unroll 4
        for (int k = 0; k < 32; ++k) {
            float w = lb[i0 + k];
            const float* f = fwd + ((size_t)a * NE + i0 + k) * NE;
            s0 = fmaf(w, f[t], s0);
            s1 = fmaf(w, f[t + 256], s1);
        }
        atomicAdd(&bvec[a * NE + t], s0);
        atomicAdd(&bvec[a * NE + t + 256], s1);
    }
}

// TM[m=k'(1024)][n=(a,j)(4096)] = sum_i lwT[m][i]*fwdT[n][i]; store TMT[n][m] bf16
__global__ __launch_bounds__(256) void k_prep(const uint16_t* __restrict__ lwT,
                                              const uint16_t* __restrict__ fwdT,
                                              uint16_t* __restrict__ TMT) {
    __shared__ alignas(16) uint16_t lA[128 * 32];
    __shared__ alignas(16) uint16_t lB[128 * 32];
    int bz = blockIdx.x;
    int nt = bz & 31, mt = bz >> 5;
    int m0 = mt * 128, n0 = nt * 128;
    int t = threadIdx.x, lane = t & 63;
    int w = t >> 6, wm = w >> 1, wn = w & 1;
    int lr = lane & 15, lc = lane >> 4;
    int sl = swz(lr);
    f32x4 acc[4][4] = {};
    for (int k0 = 0; k0 < NE; k0 += 32) {
        __syncthreads();
#pragma unroll
        for (int p = 0; p < 2; ++p) {
            int idx = p * 256 + t;
            int row = idx >> 2, c16 = (idx & 3) ^ swz(row);
            gl_lds16(lwT + (size_t)(m0 + row) * NE + k0 + c16 * 8, lA + idx * 8);
            gl_lds16(fwdT + (size_t)(n0 + row) * NE + k0 + c16 * 8, lB + idx * 8);
        }
        __syncthreads();
        bf16x8 af[4], bfr[4];
#pragma unroll
        for (int i = 0; i < 4; ++i)
            af[i] = *(const bf16x8*)&lA[(wm * 64 + i * 16 + lr) * 32 + ((lc ^ sl) << 3)];
#pragma unroll
        for (int j = 0; j < 4; ++j)
            bfr[j] = *(const bf16x8*)&lB[(wn * 64 + j * 16 + lr) * 32 + ((lc ^ sl) << 3)];
#pragma unroll
        for (int i = 0; i < 4; ++i)
#pragma unroll
            for (int j = 0; j < 4; ++j)
                acc[i][j] = __builtin_amdgcn_mfma_f32_16x16x32_bf16(af[i], bfr[j], acc[i][j], 0, 0, 0);
    }
#pragma unroll
    for (int i = 0; i < 4; ++i) {
        int mb = m0 + wm * 64 + i * 16 + lc * 4;
#pragma unroll
        for (int j = 0; j < 4; ++j) {
            int n = n0 + wn * 64 + j * 16 + lr;
            ushort4 v;
            v.x = cvt_bf16(acc[i][j][0]);
            v.y = cvt_bf16(acc[i][j][1]);
            v.z = cvt_bf16(acc[i][j][2]);
            v.w = cvt_bf16(acc[i][j][3]);
            *(ushort4*)&TMT[(size_t)n * NK + mb] = v;
        }
    }
}

// attr[b,a,j] = img[b]@TM_a[0:512] + edge[b,a]@TM_a[512:1024] + bvec_a[j]
// 256 thr / 4 waves, 128x256 tile (wave tile 64x128 -> 32 MFMA/wave/step),
// BK=32 dbuf, cf_pos layout, a=XCD, T14 edge-f32 fuse, nontemporal attr.
// Same LDS (48 KB -> 3 blocks/CU = 12 waves) as R12 but 3 independent
// barrier groups and doubled per-wave MFMA cluster.
template<bool WB>
__global__ __launch_bounds__(256) void k_mm8(const uint16_t* __restrict__ imgb,
                                             const float* __restrict__ edge,
                                             const uint16_t* __restrict__ TMT,
                                             const float* __restrict__ bvec,
                                             float* __restrict__ attr,
                                             uint16_t* __restrict__ attrb) {
    __shared__ alignas(16) uint16_t lA[2][128 * 32];   // 2 x 8 KB
    __shared__ alignas(16) uint16_t lB[2][256 * 32];   // 2 x 16 KB
    int o = blockIdx.x;             // 2048 = 8 xcd * (2 jt * 128 mt)
    int a = o & 7, idx = o >> 3;
    int jt = idx & 1, mt = idx >> 1;
    int m0 = mt * 128, jb = jt * 256;
    int t = threadIdx.x, lane = t & 63;
    int w = t >> 6, wm = w >> 1, wn = w & 1;   // wave tile: rows wm*64.., cols wn*128..
    int lr = lane & 15, lc = lane >> 4;
    // A stage map (2 units/thread): inverse of cf_pos
    int srA[2], scA[2];
#pragma unroll
    for (int p = 0; p < 2; ++p) {
        int u = t + p * 256;
        int rp = u >> 3, q = (u & 7) ^ (rp & 7);
        srA[p] = (rp << 1) | (q >> 2);
        scA[p] = (q & 3) << 3;
    }
    // B stage map (4 units/thread)
    int srB[4], scB[4];
#pragma unroll
    for (int p = 0; p < 4; ++p) {
        int u = t + p * 256;
        int rp = u >> 3, q = (u & 7) ^ (rp & 7);
        srB[p] = (rp << 1) | (q >> 2);
        scB[p] = (q & 3) << 3;
    }
    // edge f32 path: 2 natural (row, chunk) slots/thread, write swizzled
    int er[2], ec[2], epos[2];
#pragma unroll
    for (int p = 0; p < 2; ++p) {
        int u = t + p * 256;
        er[p] = u >> 2; ec[p] = u & 3;
        epos[p] = cf_pos(er[p], ec[p]) * 8;
    }
    int aoff[4], boff[8];
#pragma unroll
    for (int i = 0; i < 4; ++i)
        aoff[i] = cf_pos(wm * 64 + i * 16 + lr, lc) * 8;
#pragma unroll
    for (int j = 0; j < 8; ++j)
        boff[j] = cf_pos(wn * 128 + j * 16 + lr, lc) * 8;
    auto stage_img = [&](int buf, int s) {
#pragma unroll
        for (int p = 0; p < 2; ++p)
            gl_lds16(imgb + (size_t)(m0 + srA[p]) * NE + s * 32 + scA[p],
                     &lA[buf][(t + p * 256) * 8]);
    };
    auto stage_tmt = [&](int buf, int s) {
#pragma unroll
        for (int p = 0; p < 4; ++p)
            gl_lds16(TMT + (size_t)(a * NE + jb + srB[p]) * NK + s * 32 + scB[p],
                     &lB[buf][(t + p * 256) * 8]);
    };
    f32x4 acc[4][8] = {};
    stage_img(0, 0);
    stage_tmt(0, 0);
    for (int s = 0; s < 32; ++s) {
        int cur = s & 1, nb = cur ^ 1;
        __syncthreads();
        float4 e[2][2];
        bool eN = (s < 31) && (s + 1 >= 16);
        if (s < 31) {
            if (s + 1 < 16) {
                stage_img(nb, s + 1);
            } else {
                int kk = (s + 1 - 16) * 32;
#pragma unroll
                for (int p = 0; p < 2; ++p) {
                    const float* sp = edge + ((size_t)(m0 + er[p]) * NA + a) * NE + kk + ec[p] * 8;
                    e[p][0] = ((const float4*)sp)[0];
                    e[p][1] = ((const float4*)sp)[1];
                }
            }
            stage_tmt(nb, s + 1);
        }
        bf16x8 af[4], bfr[8];
#pragma unroll
        for (int i = 0; i < 4; ++i) af[i] = *(const bf16x8*)&lA[cur][aoff[i]];
#pragma unroll
        for (int j = 0; j < 8; ++j) bfr[j] = *(const bf16x8*)&lB[cur][boff[j]];
#pragma unroll
        for (int i = 0; i < 4; ++i)
#pragma unroll
            for (int j = 0; j < 8; ++j)
                acc[i][j] = __builtin_amdgcn_mfma_f32_16x16x32_bf16(af[i], bfr[j], acc[i][j], 0, 0, 0);
        if (eN) {
#pragma unroll
            for (int p = 0; p < 2; ++p) {
                u16x8 ov = {cvt_bf16(e[p][0].x), cvt_bf16(e[p][0].y),
                            cvt_bf16(e[p][0].z), cvt_bf16(e[p][0].w),
                            cvt_bf16(e[p][1].x), cvt_bf16(e[p][1].y),
                            cvt_bf16(e[p][1].z), cvt_bf16(e[p][1].w)};
                *(u16x8*)&lA[nb][epos[p]] = ov;
            }
        }
    }
#pragma unroll
    for (int j = 0; j < 8; ++j) {
        float bv = bvec[a * NE + jb + wn * 128 + j * 16 + lr];
#pragma unroll
        for (int i = 0; i < 4; ++i)
#pragma unroll
            for (int r = 0; r < 4; ++r)
                acc[i][j][r] += bv;
    }
#pragma unroll
    for (int i = 0; i < 4; ++i) {
#pragma unroll
        for (int r = 0; r < 4; ++r) {
            int bm = m0 + wm * 64 + i * 16 + lc * 4 + r;
            float* orow = attr + ((size_t)bm * NA + a) * NE + jb;
#pragma unroll
            for (int j = 0; j < 8; ++j)
                __builtin_nontemporal_store(acc[i][j][r], &orow[wn * 128 + j * 16 + lr]);
            if (WB) {
                uint16_t* brw = attrb + ((size_t)bm * NA + a) * NE + jb;
#pragma unroll
                for (int j = 0; j < 8; ++j)
                    brw[wn * 128 + j * 16 + lr] = cvt_bf16(acc[i][j][r]);
            }
        }
    }
}

// ind[b,j] += sum_{a in half} sw[a]*relu(attrb[b,a,:]@bwd_a[:,j])
// R7/R12 winner verbatim: 256 thr, 128x128, BK=32 dbuf, cf_pos, (jt,ah)=XCD, a-split-2.
template<bool AB>
__global__ __launch_bounds__(256) void k_ind4(const float* __restrict__ attrf,
                                              const uint16_t* __restrict__ attrb,
                                              const uint16_t* __restrict__ bwdT,
                                              const float* __restrict__ sw,
                                              float* __restrict__ ind) {
    __shared__ alignas(16) uint16_t lA[2][128 * 32];
    __shared__ alignas(16) uint16_t lB[2][128 * 32];
    int o = blockIdx.x;            // 1024 = 8 xcd * 128 mt
    int xcd = o & 7, mt = o >> 3;
    int jt = xcd >> 1, ah = xcd & 1;
    int m0 = mt * 128, jb = jt * 128, a0 = ah * 4;
    int t = threadIdx.x, lane = t & 63;
    int w = t >> 6, wm = w >> 1, wn = w & 1;
    int lr = lane & 15, lc = lane >> 4;
    int srow[2], sc8[2];
#pragma unroll
    for (int p = 0; p < 2; ++p) {
        int u = p * 256 + t;
        int rp = u >> 3, q = (u & 7) ^ (rp & 7);
        srow[p] = (rp << 1) | (q >> 2);
        sc8[p] = (q & 3) << 3;
    }
    int erow[2], ec[2], epos[2];
#pragma unroll
    for (int p = 0; p < 2; ++p) {
        int u = p * 256 + t;
        erow[p] = u >> 2; ec[p] = u & 3;
        epos[p] = cf_pos(erow[p], ec[p]) * 8;
    }
    int aoff[4], boff[4];
#pragma unroll
    for (int i = 0; i < 4; ++i) {
        aoff[i] = cf_pos(wm * 64 + i * 16 + lr, lc) * 8;
        boff[i] = cf_pos(wn * 64 + i * 16 + lr, lc) * 8;
    }
    auto stage = [&](int buf, int s) {
        int aa = a0 + (s >> 4), kk = (s & 15) * 32;
        if (AB) {
#pragma unroll
            for (int p = 0; p < 2; ++p)
                gl_lds16(attrb + ((size_t)(m0 + srow[p]) * NA + aa) * NE + kk + sc8[p],
                         &lA[buf][(p * 256 + t) * 8]);
        } else {
#pragma unroll
            for (int p = 0; p < 2; ++p) {
                const float* sp = attrf + ((size_t)(m0 + erow[p]) * NA + aa) * NE + kk + ec[p] * 8;
                float4 v0 = ((const float4*)sp)[0];
                float4 v1 = ((const float4*)sp)[1];
                u16x8 ov = {cvt_bf16(v0.x), cvt_bf16(v0.y), cvt_bf16(v0.z), cvt_bf16(v0.w),
                            cvt_bf16(v1.x), cvt_bf16(v1.y), cvt_bf16(v1.z), cvt_bf16(v1.w)};
                *(u16x8*)&lA[buf][epos[p]] = ov;
            }
        }
#pragma unroll
        for (int p = 0; p < 2; ++p)
            gl_lds16(bwdT + (size_t)(aa * NE + jb + srow[p]) * NE + kk + sc8[p],
                     &lB[buf][(p * 256 + t) * 8]);
    };
    f32x4 res[4][4] = {};
    f32x4 acc[4][4] = {};
    stage(0, 0);
    for (int s = 0; s < 64; ++s) {
        int cur = s & 1;
        __syncthreads();
        if (s < 63) stage(cur ^ 1, s + 1);
        bf16x8 af[4], bfr[4];
#pragma unroll
        for (int i = 0; i < 4; ++i) af[i] = *(const bf16x8*)&lA[cur][aoff[i]];
#pragma unroll
        for (int j = 0; j < 4; ++j) bfr[j] = *(const bf16x8*)&lB[cur][boff[j]];
#pragma unroll
        for (int i = 0; i < 4; ++i)
#pragma unroll
            for (int j = 0; j < 4; ++j)
                acc[i][j] = __builtin_amdgcn_mfma_f32_16x16x32_bf16(af[i], bfr[j], acc[i][j], 0, 0, 0);
        if ((s & 15) == 15) {
            float wa = sw[a0 + (s >> 4)];
#pragma unroll
            for (int i = 0; i < 4; ++i)
#pragma unroll
                for (int j = 0; j < 4; ++j) {
#pragma unroll
                    for (int r = 0; r < 4; ++r)
                        res[i][j][r] += wa * fmaxf(acc[i][j][r], 0.f);
                    acc[i][j] = (f32x4){0.f, 0.f, 0.f, 0.f};
                }
        }
    }
#pragma unroll
    for (int i = 0; i < 4; ++i) {
#pragma unroll
        for (int r = 0; r < 4; ++r) {
            int bm = m0 + wm * 64 + i * 16 + lc * 4 + r;
            float* orow = ind + (size_t)bm * NE + jb;
#pragma unroll
            for (int j = 0; j < 4; ++j)
                atomicAdd(&orow[wn * 64 + j * 16 + lr], res[i][j][r]);
        }
    }
}

extern "C" void kernel_launch(void* const* d_in, const int* in_sizes, int n_in,
                              void* d_out, int out_size, void* d_ws, size_t ws_size,
                              hipStream_t stream) {
    (void)in_sizes; (void)n_in; (void)out_size;
    const float* img  = (const float*)d_in[0];
    const float* edge = (const float*)d_in[1];
    const float* lw   = (const float*)d_in[2];
    const float* lb   = (const float*)d_in[3];
    const float* fwd  = (const float*)d_in[4];
    const float* bwd  = (const float*)d_in[5];
    const float* sw   = (const float*)d_in[6];
    float* attr = (float*)d_out;
    float* ind  = attr + (size_t)NB * NA * NE;

    char* ws = (char*)d_ws;
    size_t off = 0;
    auto alloc = [&](size_t bytes) { void* p = ws + off; off += bytes; return p; };
    uint16_t* lwT  = (uint16_t*)alloc((size_t)NK * NE * 2);       // 1 MB
    uint16_t* fwdT = (uint16_t*)alloc((size_t)NA * NE * NE * 2);  // 4 MB
    uint16_t* bwdT = (uint16_t*)alloc((size_t)NA * NE * NE * 2);  // 4 MB
    uint16_t* TMT  = (uint16_t*)alloc((size_t)NN * NK * 2);       // 8 MB
    uint16_t* imgb = (uint16_t*)alloc((size_t)NB * NE * 2);       // 16 MB
    float*    bvec = (float*)alloc((size_t)NN * 4);               // 16 KB

    const size_t BIGB = (size_t)NB * NA * NE * 2;  // 128 MB
    bool has_attrb = ws_size >= off + BIGB;
    uint16_t* attrb = has_attrb ? (uint16_t*)alloc(BIGB) : (uint16_t*)0;

    hipMemsetAsync(bvec, 0, (size_t)NN * 4, stream);
    hipMemsetAsync(ind, 0, (size_t)NB * NE * 4, stream);

    k_pre<<<12928, 256, 0, stream>>>(lw, fwd, bwd, img, lb, lwT, fwdT, bwdT, imgb, bvec);
    k_prep<<<(NK / 128) * (NN / 128), 256, 0, stream>>>(lwT, fwdT, TMT);

    int mm_grid = 8 * 2 * (NB / 128);            // 2048 blocks of 256 threads
    int ind_grid = (NB / 128) * (NE / 128) * 2;  // 1024 blocks of 256 threads

    if (has_attrb) {
        k_mm8<true><<<mm_grid, 256, 0, stream>>>(imgb, edge, TMT, bvec, attr, attrb);
        k_ind4<true><<<ind_grid, 256, 0, stream>>>(attr, attrb, bwdT, sw, ind);
    } else {
        k_mm8<false><<<mm_grid, 256, 0, stream>>>(imgb, edge, TMT, bvec, attr, attrb);
        k_ind4<false><<<ind_grid, 256, 0, stream>>>(attr, attrb, bwdT, sw, ind);
    }
}

// Round 15
// 433.280 us; speedup vs baseline: 1.2724x; 1.2724x over previous
//
#include <hip/hip_runtime.h>
#include <cstdint>
#include <cstddef>

#define NB 16384
#define NA 8
#define NE 512
#define NK 1024   // 2E
#define NN 4096   // A*E

typedef __bf16 bf16x8 __attribute__((ext_vector_type(8)));
typedef float  f32x4  __attribute__((ext_vector_type(4)));
typedef uint16_t u16x8 __attribute__((ext_vector_type(8)));

__device__ __forceinline__ uint16_t cvt_bf16(float f) {
    uint32_t u = __builtin_bit_cast(uint32_t, f);
    u += 0x7fffu + ((u >> 16) & 1u);
    return (uint16_t)(u >> 16);
}

// legacy BK=32 chunk swizzle (k_prep only)
__device__ __forceinline__ int swz(int row) { return (row ^ (row >> 2)) & 3; }

// conflict-free BK=32 tile position (16B units): row-pair interleave + 3-bit XOR
// proven 0-conflict in R5..R14 PMC
__device__ __forceinline__ int cf_pos(int row, int c) {
    return ((row >> 1) << 3) + ((((row & 1) << 2) + c) ^ ((row >> 1) & 7));
}

__device__ __forceinline__ void gl_lds16(const void* g, void* l) {
    __builtin_amdgcn_global_load_lds(
        (__attribute__((address_space(1))) void*)(void*)g,
        (__attribute__((address_space(3))) void*)l, 16, 0, 0);
}

// ---- fused prep: lw/fwd/bwd transpose-cvt + img cvt + bvec, one launch ----
__device__ __forceinline__ void tcvt_tile(const float* __restrict__ src,
                                          uint16_t* __restrict__ dst,
                                          int R, int C, int c0, int r0, int t) {
    __shared__ float tile[32][33];
    int tx = t & 31, ty = t >> 5;
#pragma unroll
    for (int yy = 0; yy < 4; ++yy) {
        int r = ty + yy * 8;
        tile[r][tx] = src[(size_t)(r0 + r) * C + c0 + tx];
    }
    __syncthreads();
#pragma unroll
    for (int yy = 0; yy < 4; ++yy) {
        int c = ty + yy * 8;
        dst[(size_t)(c0 + c) * R + r0 + tx] = cvt_bf16(tile[tx][c]);
    }
}

__global__ __launch_bounds__(256) void k_pre(const float* __restrict__ lw,
                                             const float* __restrict__ fwd,
                                             const float* __restrict__ bwd,
                                             const float* __restrict__ img,
                                             const float* __restrict__ lb,
                                             uint16_t* __restrict__ lwT,
                                             uint16_t* __restrict__ fwdT,
                                             uint16_t* __restrict__ bwdT,
                                             uint16_t* __restrict__ imgb,
                                             float* __restrict__ bvec) {
    int b = blockIdx.x, t = threadIdx.x;
    if (b < 512) {
        int bx = b & 31, by = b >> 5;
        tcvt_tile(lw, lwT, NE, NK, bx * 32, by * 32, t);
    } else if (b < 2560) {
        int i = b - 512;
        int mat = i >> 8, bx = i & 15, by = (i >> 4) & 15;
        tcvt_tile(fwd + (size_t)mat * NE * NE, fwdT + (size_t)mat * NE * NE,
                  NE, NE, bx * 32, by * 32, t);
    } else if (b < 4608) {
        int i = b - 2560;
        int mat = i >> 8, bx = i & 15, by = (i >> 4) & 15;
        tcvt_tile(bwd + (size_t)mat * NE * NE, bwdT + (size_t)mat * NE * NE,
                  NE, NE, bx * 32, by * 32, t);
    } else if (b < 12800) {
        int i = (b - 4608) * 256 + t;
        float4 v = ((const float4*)img)[i];
        ushort4 o;
        o.x = cvt_bf16(v.x); o.y = cvt_bf16(v.y); o.z = cvt_bf16(v.z); o.w = cvt_bf16(v.w);
        ((ushort4*)imgb)[i] = o;
    } else {
        int i = b - 12800;
        int a = i >> 4, i0 = (i & 15) * 32;
        float s0 = 0.f, s1 = 0.f;
#pragma unroll 4
        for (int k = 0; k < 32; ++k) {
            float w = lb[i0 + k];
            const float* f = fwd + ((size_t)a * NE + i0 + k) * NE;
            s0 = fmaf(w, f[t], s0);
            s1 = fmaf(w, f[t + 256], s1);
        }
        atomicAdd(&bvec[a * NE + t], s0);
        atomicAdd(&bvec[a * NE + t + 256], s1);
    }
}

// TM[m=k'(1024)][n=(a,j)(4096)] = sum_i lwT[m][i]*fwdT[n][i]; store TMT[n][m] bf16
__global__ __launch_bounds__(256) void k_prep(const uint16_t* __restrict__ lwT,
                                              const uint16_t* __restrict__ fwdT,
                                              uint16_t* __restrict__ TMT) {
    __shared__ alignas(16) uint16_t lA[128 * 32];
    __shared__ alignas(16) uint16_t lB[128 * 32];
    int bz = blockIdx.x;
    int nt = bz & 31, mt = bz >> 5;
    int m0 = mt * 128, n0 = nt * 128;
    int t = threadIdx.x, lane = t & 63;
    int w = t >> 6, wm = w >> 1, wn = w & 1;
    int lr = lane & 15, lc = lane >> 4;
    int sl = swz(lr);
    f32x4 acc[4][4] = {};
    for (int k0 = 0; k0 < NE; k0 += 32) {
        __syncthreads();
#pragma unroll
        for (int p = 0; p < 2; ++p) {
            int idx = p * 256 + t;
            int row = idx >> 2, c16 = (idx & 3) ^ swz(row);
            gl_lds16(lwT + (size_t)(m0 + row) * NE + k0 + c16 * 8, lA + idx * 8);
            gl_lds16(fwdT + (size_t)(n0 + row) * NE + k0 + c16 * 8, lB + idx * 8);
        }
        __syncthreads();
        bf16x8 af[4], bfr[4];
#pragma unroll
        for (int i = 0; i < 4; ++i)
            af[i] = *(const bf16x8*)&lA[(wm * 64 + i * 16 + lr) * 32 + ((lc ^ sl) << 3)];
#pragma unroll
        for (int j = 0; j < 4; ++j)
            bfr[j] = *(const bf16x8*)&lB[(wn * 64 + j * 16 + lr) * 32 + ((lc ^ sl) << 3)];
#pragma unroll
        for (int i = 0; i < 4; ++i)
#pragma unroll
            for (int j = 0; j < 4; ++j)
                acc[i][j] = __builtin_amdgcn_mfma_f32_16x16x32_bf16(af[i], bfr[j], acc[i][j], 0, 0, 0);
    }
#pragma unroll
    for (int i = 0; i < 4; ++i) {
        int mb = m0 + wm * 64 + i * 16 + lc * 4;
#pragma unroll
        for (int j = 0; j < 4; ++j) {
            int n = n0 + wn * 64 + j * 16 + lr;
            ushort4 v;
            v.x = cvt_bf16(acc[i][j][0]);
            v.y = cvt_bf16(acc[i][j][1]);
            v.z = cvt_bf16(acc[i][j][2]);
            v.w = cvt_bf16(acc[i][j][3]);
            *(ushort4*)&TMT[(size_t)n * NK + mb] = v;
        }
    }
}

// attr[b,a,j] = img[b]@TM_a[0:512] + edge[b,a]@TM_a[512:1024] + bvec_a[j]
// 1024 thr / 16 waves (4x4), 128x512 tile (wave tile 32x128), BK=32 dbuf,
// cf_pos layout, a=XCD (one block covers ALL of a's N -> A staged once),
// T14 edge-f32 fuse on waves 0-7, nontemporal attr. LDS 80 KB -> 2 blocks/CU.
template<bool WB>
__global__ __launch_bounds__(1024) void k_mm9(const uint16_t* __restrict__ imgb,
                                              const float* __restrict__ edge,
                                              const uint16_t* __restrict__ TMT,
                                              const float* __restrict__ bvec,
                                              float* __restrict__ attr,
                                              uint16_t* __restrict__ attrb) {
    __shared__ alignas(16) uint16_t lA[2][128 * 32];   // 2 x 8 KB
    __shared__ alignas(16) uint16_t lB[2][512 * 32];   // 2 x 32 KB
    int o = blockIdx.x;             // 1024 = 8 xcd * 128 mt
    int a = o & 7, mt = o >> 3;
    int m0 = mt * 128;
    int t = threadIdx.x, lane = t & 63;
    int w = t >> 6, wm = w >> 2, wn = w & 3;   // wave tile: rows wm*32.., cols wn*128..
    int lr = lane & 15, lc = lane >> 4;
    // A stage map (waves 0-7, 1 unit/thread): inverse of cf_pos
    int rpA = t >> 3, qA = (t & 7) ^ (rpA & 7);
    int srA = (rpA << 1) | (qA >> 2), scA = (qA & 3) << 3;
    // B stage map (all threads, 2 units/thread)
    int srB[2], scB[2];
#pragma unroll
    for (int p = 0; p < 2; ++p) {
        int u = t + p * 1024;
        int rp = u >> 3, q = (u & 7) ^ (rp & 7);
        srB[p] = (rp << 1) | (q >> 2);
        scB[p] = (q & 3) << 3;
    }
    // edge f32 path (waves 0-7): thread owns (row, chunk) natural, writes swizzled
    int er = t >> 2, ec = t & 3;
    int epos = cf_pos(er, ec) * 8;
    int aoff[2], boff[8];
#pragma unroll
    for (int i = 0; i < 2; ++i)
        aoff[i] = cf_pos(wm * 32 + i * 16 + lr, lc) * 8;
#pragma unroll
    for (int j = 0; j < 8; ++j)
        boff[j] = cf_pos(wn * 128 + j * 16 + lr, lc) * 8;
    auto stage_img = [&](int buf, int s) {
        if (t < 512)
            gl_lds16(imgb + (size_t)(m0 + srA) * NE + s * 32 + scA, &lA[buf][t * 8]);
    };
    auto stage_tmt = [&](int buf, int s) {
#pragma unroll
        for (int p = 0; p < 2; ++p)
            gl_lds16(TMT + (size_t)(a * NE + srB[p]) * NK + s * 32 + scB[p],
                     &lB[buf][(t + p * 1024) * 8]);
    };
    f32x4 acc[2][8] = {};
    stage_img(0, 0);
    stage_tmt(0, 0);
    for (int s = 0; s < 32; ++s) {
        int cur = s & 1, nb = cur ^ 1;
        __syncthreads();
        float4 e0, e1;
        bool eN = (s < 31) && (s + 1 >= 16);
        if (s < 31) {
            if (s + 1 < 16) {
                stage_img(nb, s + 1);
            } else if (t < 512) {
                int kk = (s + 1 - 16) * 32;
                const float* sp = edge + ((size_t)(m0 + er) * NA + a) * NE + kk + ec * 8;
                e0 = ((const float4*)sp)[0];
                e1 = ((const float4*)sp)[1];
            }
            stage_tmt(nb, s + 1);
        }
        bf16x8 af[2], bfr[8];
#pragma unroll
        for (int i = 0; i < 2; ++i) af[i] = *(const bf16x8*)&lA[cur][aoff[i]];
#pragma unroll
        for (int j = 0; j < 8; ++j) bfr[j] = *(const bf16x8*)&lB[cur][boff[j]];
#pragma unroll
        for (int i = 0; i < 2; ++i)
#pragma unroll
            for (int j = 0; j < 8; ++j)
                acc[i][j] = __builtin_amdgcn_mfma_f32_16x16x32_bf16(af[i], bfr[j], acc[i][j], 0, 0, 0);
        if (eN && t < 512) {
            u16x8 ov = {cvt_bf16(e0.x), cvt_bf16(e0.y), cvt_bf16(e0.z), cvt_bf16(e0.w),
                        cvt_bf16(e1.x), cvt_bf16(e1.y), cvt_bf16(e1.z), cvt_bf16(e1.w)};
            *(u16x8*)&lA[nb][epos] = ov;
        }
    }
#pragma unroll
    for (int j = 0; j < 8; ++j) {
        float bv = bvec[a * NE + wn * 128 + j * 16 + lr];
#pragma unroll
        for (int i = 0; i < 2; ++i)
#pragma unroll
            for (int r = 0; r < 4; ++r)
                acc[i][j][r] += bv;
    }
#pragma unroll
    for (int i = 0; i < 2; ++i) {
#pragma unroll
        for (int r = 0; r < 4; ++r) {
            int bm = m0 + wm * 32 + i * 16 + lc * 4 + r;
            float* orow = attr + ((size_t)bm * NA + a) * NE;
#pragma unroll
            for (int j = 0; j < 8; ++j)
                __builtin_nontemporal_store(acc[i][j][r], &orow[wn * 128 + j * 16 + lr]);
            if (WB) {
                uint16_t* brw = attrb + ((size_t)bm * NA + a) * NE;
#pragma unroll
                for (int j = 0; j < 8; ++j)
                    brw[wn * 128 + j * 16 + lr] = cvt_bf16(acc[i][j][r]);
            }
        }
    }
}

// ind[b,j] += sum_{a in half} sw[a]*relu(attrb[b,a,:]@bwd_a[:,j])
// R7/R12 winner verbatim: 256 thr, 128x128, BK=32 dbuf, cf_pos, (jt,ah)=XCD, a-split-2.
template<bool AB>
__global__ __launch_bounds__(256) void k_ind4(const float* __restrict__ attrf,
                                              const uint16_t* __restrict__ attrb,
                                              const uint16_t* __restrict__ bwdT,
                                              const float* __restrict__ sw,
                                              float* __restrict__ ind) {
    __shared__ alignas(16) uint16_t lA[2][128 * 32];
    __shared__ alignas(16) uint16_t lB[2][128 * 32];
    int o = blockIdx.x;            // 1024 = 8 xcd * 128 mt
    int xcd = o & 7, mt = o >> 3;
    int jt = xcd >> 1, ah = xcd & 1;
    int m0 = mt * 128, jb = jt * 128, a0 = ah * 4;
    int t = threadIdx.x, lane = t & 63;
    int w = t >> 6, wm = w >> 1, wn = w & 1;
    int lr = lane & 15, lc = lane >> 4;
    int srow[2], sc8[2];
#pragma unroll
    for (int p = 0; p < 2; ++p) {
        int u = p * 256 + t;
        int rp = u >> 3, q = (u & 7) ^ (rp & 7);
        srow[p] = (rp << 1) | (q >> 2);
        sc8[p] = (q & 3) << 3;
    }
    int erow[2], ec[2], epos[2];
#pragma unroll
    for (int p = 0; p < 2; ++p) {
        int u = p * 256 + t;
        erow[p] = u >> 2; ec[p] = u & 3;
        epos[p] = cf_pos(erow[p], ec[p]) * 8;
    }
    int aoff[4], boff[4];
#pragma unroll
    for (int i = 0; i < 4; ++i) {
        aoff[i] = cf_pos(wm * 64 + i * 16 + lr, lc) * 8;
        boff[i] = cf_pos(wn * 64 + i * 16 + lr, lc) * 8;
    }
    auto stage = [&](int buf, int s) {
        int aa = a0 + (s >> 4), kk = (s & 15) * 32;
        if (AB) {
#pragma unroll
            for (int p = 0; p < 2; ++p)
                gl_lds16(attrb + ((size_t)(m0 + srow[p]) * NA + aa) * NE + kk + sc8[p],
                         &lA[buf][(p * 256 + t) * 8]);
        } else {
#pragma unroll
            for (int p = 0; p < 2; ++p) {
                const float* sp = attrf + ((size_t)(m0 + erow[p]) * NA + aa) * NE + kk + ec[p] * 8;
                float4 v0 = ((const float4*)sp)[0];
                float4 v1 = ((const float4*)sp)[1];
                u16x8 ov = {cvt_bf16(v0.x), cvt_bf16(v0.y), cvt_bf16(v0.z), cvt_bf16(v0.w),
                            cvt_bf16(v1.x), cvt_bf16(v1.y), cvt_bf16(v1.z), cvt_bf16(v1.w)};
                *(u16x8*)&lA[buf][epos[p]] = ov;
            }
        }
#pragma unroll
        for (int p = 0; p < 2; ++p)
            gl_lds16(bwdT + (size_t)(aa * NE + jb + srow[p]) * NE + kk + sc8[p],
                     &lB[buf][(p * 256 + t) * 8]);
    };
    f32x4 res[4][4] = {};
    f32x4 acc[4][4] = {};
    stage(0, 0);
    for (int s = 0; s < 64; ++s) {
        int cur = s & 1;
        __syncthreads();
        if (s < 63) stage(cur ^ 1, s + 1);
        bf16x8 af[4], bfr[4];
#pragma unroll
        for (int i = 0; i < 4; ++i) af[i] = *(const bf16x8*)&lA[cur][aoff[i]];
#pragma unroll
        for (int j = 0; j < 4; ++j) bfr[j] = *(const bf16x8*)&lB[cur][boff[j]];
#pragma unroll
        for (int i = 0; i < 4; ++i)
#pragma unroll
            for (int j = 0; j < 4; ++j)
                acc[i][j] = __builtin_amdgcn_mfma_f32_16x16x32_bf16(af[i], bfr[j], acc[i][j], 0, 0, 0);
        if ((s & 15) == 15) {
            float wa = sw[a0 + (s >> 4)];
#pragma unroll
            for (int i = 0; i < 4; ++i)
#pragma unroll
                for (int j = 0; j < 4; ++j) {
#pragma unroll
                    for (int r = 0; r < 4; ++r)
                        res[i][j][r] += wa * fmaxf(acc[i][j][r], 0.f);
                    acc[i][j] = (f32x4){0.f, 0.f, 0.f, 0.f};
                }
        }
    }
#pragma unroll
    for (int i = 0; i < 4; ++i) {
#pragma unroll
        for (int r = 0; r < 4; ++r) {
            int bm = m0 + wm * 64 + i * 16 + lc * 4 + r;
            float* orow = ind + (size_t)bm * NE + jb;
#pragma unroll
            for (int j = 0; j < 4; ++j)
                atomicAdd(&orow[wn * 64 + j * 16 + lr], res[i][j][r]);
        }
    }
}

extern "C" void kernel_launch(void* const* d_in, const int* in_sizes, int n_in,
                              void* d_out, int out_size, void* d_ws, size_t ws_size,
                              hipStream_t stream) {
    (void)in_sizes; (void)n_in; (void)out_size;
    const float* img  = (const float*)d_in[0];
    const float* edge = (const float*)d_in[1];
    const float* lw   = (const float*)d_in[2];
    const float* lb   = (const float*)d_in[3];
    const float* fwd  = (const float*)d_in[4];
    const float* bwd  = (const float*)d_in[5];
    const float* sw   = (const float*)d_in[6];
    float* attr = (float*)d_out;
    float* ind  = attr + (size_t)NB * NA * NE;

    char* ws = (char*)d_ws;
    size_t off = 0;
    auto alloc = [&](size_t bytes) { void* p = ws + off; off += bytes; return p; };
    uint16_t* lwT  = (uint16_t*)alloc((size_t)NK * NE * 2);       // 1 MB
    uint16_t* fwdT = (uint16_t*)alloc((size_t)NA * NE * NE * 2);  // 4 MB
    uint16_t* bwdT = (uint16_t*)alloc((size_t)NA * NE * NE * 2);  // 4 MB
    uint16_t* TMT  = (uint16_t*)alloc((size_t)NN * NK * 2);       // 8 MB
    uint16_t* imgb = (uint16_t*)alloc((size_t)NB * NE * 2);       // 16 MB
    float*    bvec = (float*)alloc((size_t)NN * 4);               // 16 KB

    const size_t BIGB = (size_t)NB * NA * NE * 2;  // 128 MB
    bool has_attrb = ws_size >= off + BIGB;
    uint16_t* attrb = has_attrb ? (uint16_t*)alloc(BIGB) : (uint16_t*)0;

    hipMemsetAsync(bvec, 0, (size_t)NN * 4, stream);
    hipMemsetAsync(ind, 0, (size_t)NB * NE * 4, stream);

    k_pre<<<12928, 256, 0, stream>>>(lw, fwd, bwd, img, lb, lwT, fwdT, bwdT, imgb, bvec);
    k_prep<<<(NK / 128) * (NN / 128), 256, 0, stream>>>(lwT, fwdT, TMT);

    int mm_grid = 8 * (NB / 128);                // 1024 blocks of 1024 threads
    int ind_grid = (NB / 128) * (NE / 128) * 2;  // 1024 blocks of 256 threads

    if (has_attrb) {
        k_mm9<true><<<mm_grid, 1024, 0, stream>>>(imgb, edge, TMT, bvec, attr, attrb);
        k_ind4<true><<<ind_grid, 256, 0, stream>>>(attr, attrb, bwdT, sw, ind);
    } else {
        k_mm9<false><<<mm_grid, 1024, 0, stream>>>(imgb, edge, TMT, bvec, attr, attrb);
        k_ind4<false><<<ind_grid, 256, 0, stream>>>(attr, attrb, bwdT, sw, ind);
    }
}